// Round 6
// baseline (206.157 us; speedup 1.0000x reference)
//
#include <hip/hip_runtime.h>

// LowRankGDN: out[n,c,p] = x[n,c,p] * rsqrt( beta_r[c] + sum_r A_r[c,r] * T[n,r,p] )
//   T[n,r,p] = sum_c A_r[c,r] * x[n,c,p]^2
// Shapes: x [8,192,256,256] f32, beta [192], A [192,8]. Output f32, same shape.
//
// R6: single-HBM-read WITHOUT register-resident x. Block's x footprint
// (192ch x 128px x 4B = 98 KB) fits L2, so pass 2 RE-LOADS x (L2-hit;
// L2 agg 34.5 TB/s is not a bottleneck) instead of keeping xr[] in VGPRs.
// Per-thread state: T[8] v2 + temps ~40 VGPR -> 8 waves/SIMD.
// 512 thr = 8 slices x 64 lanes, 128 px/block (float2), CPT=24.
// LDS 39 KB -> 4 blocks/CU = 32 waves/CU = 100% occupancy target.
// Evidence: R2 (scalar, 62% occ) hit 5.7 TB/s fabric -> occupancy, not
// width, is the lever; R4/R5 lost occupancy to xr[] registers.

#define N_IMG 8
#define C_CH 192
#define R_RK 8
#define HW 65536              // 256*256
#define PXB 128               // pixels per block (64 lanes * 2)
#define CSLICES 8
#define CPT (C_CH / CSLICES)  // 24 channels per thread
#define NTHR 512
#define BLOCKS_PER_IMG (HW / PXB)    // 512

#define PEDESTAL_F 1.4551915228366852e-11f    // 2^-36
#define BOUND_A_F 3.814697265625e-06f         // 2^-18 = sqrt(pedestal)
#define BOUND_BETA_F 1.0000072759311364e-03f  // sqrt(1e-6 + 2^-36)

typedef float v2 __attribute__((ext_vector_type(2)));

__global__ __launch_bounds__(NTHR, 8) void lrgdn_kernel(
    const float* __restrict__ x,
    const float* __restrict__ beta,
    const float* __restrict__ A,
    float* __restrict__ out)
{
    __shared__ float sA[C_CH][R_RK];          // reparametrized A (6 KB)
    __shared__ float sB[C_CH];                // reparametrized beta (0.75 KB)
    __shared__ v2 sT[CSLICES][R_RK][64];      // partial T (32 KB)

    const int tid = threadIdx.x;

    // Reparametrize params into LDS (tiny)
    for (int i = tid; i < C_CH * R_RK; i += NTHR) {
        float a = fmaxf(A[i], BOUND_A_F);
        sA[i >> 3][i & 7] = a * a - PEDESTAL_F;
    }
    if (tid < C_CH) {
        float b = fmaxf(beta[tid], BOUND_BETA_F);
        sB[tid] = b * b - PEDESTAL_F;
    }
    __syncthreads();

    const int blk  = blockIdx.x;
    const int n    = blk / BLOCKS_PER_IMG;
    const int p0   = (blk % BLOCKS_PER_IMG) * PXB;
    const int lane = tid & 63;
    const int cs   = tid >> 6;          // channel slice 0..7 (uniform per wave)
    const int c0   = cs * CPT;

    const float* xn = x   + (size_t)n * (C_CH * HW) + p0 + (size_t)c0 * HW + 2 * lane;
    float*       on = out + (size_t)n * (C_CH * HW) + p0 + (size_t)c0 * HW + 2 * lane;

    // ---- pass 1: stream 24 channels, accumulate partial T (no x retention) ----
    v2 T[R_RK];
#pragma unroll
    for (int r = 0; r < R_RK; ++r) T[r] = (v2)0.f;

#pragma unroll 8
    for (int i = 0; i < CPT; ++i) {
        v2 v = *reinterpret_cast<const v2*>(xn + (size_t)i * HW);
        v2 s = v * v;
#pragma unroll
        for (int r = 0; r < R_RK; ++r) {
            T[r] += s * sA[c0 + i][r];     // uniform LDS addr -> broadcast; fma
        }
    }

    // ---- cross-slice reduce via LDS (one barrier) ----
#pragma unroll
    for (int r = 0; r < R_RK; ++r) {
        sT[cs][r][lane] = T[r];            // b64, lanes consecutive: conflict-free
    }
    __syncthreads();

#pragma unroll
    for (int r = 0; r < R_RK; ++r) {
        v2 a01 = sT[0][r][lane] + sT[1][r][lane];
        v2 a23 = sT[2][r][lane] + sT[3][r][lane];
        v2 a45 = sT[4][r][lane] + sT[5][r][lane];
        v2 a67 = sT[6][r][lane] + sT[7][r][lane];
        T[r] = (a01 + a23) + (a45 + a67);
    }

    // ---- pass 2: re-load x (L2-hit: block footprint 98 KB), compute, store ----
#pragma unroll 8
    for (int i = 0; i < CPT; ++i) {
        int c = c0 + i;
        v2 v = *reinterpret_cast<const v2*>(xn + (size_t)i * HW);
        v2 d;
        d.x = sB[c];
        d.y = d.x;
#pragma unroll
        for (int r = 0; r < R_RK; ++r) {
            d += sA[c][r] * T[r];
        }
        v2 o;
        o.x = v.x * __builtin_amdgcn_rsqf(d.x);
        o.y = v.y * __builtin_amdgcn_rsqf(d.y);
        __builtin_nontemporal_store(o, reinterpret_cast<v2*>(on + (size_t)i * HW));
    }
}

extern "C" void kernel_launch(void* const* d_in, const int* in_sizes, int n_in,
                              void* d_out, int out_size, void* d_ws, size_t ws_size,
                              hipStream_t stream) {
    const float* x    = (const float*)d_in[0];
    const float* beta = (const float*)d_in[1];
    const float* A    = (const float*)d_in[2];
    float* out = (float*)d_out;

    dim3 grid(N_IMG * BLOCKS_PER_IMG);   // 4096 blocks
    dim3 block(NTHR);                    // 512
    hipLaunchKernelGGL(lrgdn_kernel, grid, block, 0, stream, x, beta, A, out);
}

// Round 7
// 170.067 us; speedup vs baseline: 1.2122x; 1.2122x over previous
//
#include <hip/hip_runtime.h>

// LowRankGDN: out[n,c,p] = x[n,c,p] * rsqrt( beta_r[c] + sum_r A_r[c,r] * T[n,r,p] )
//   T[n,r,p] = sum_c A_r[c,r] * x[n,c,p]^2
// Shapes: x [8,192,256,256] f32, beta [192], A [192,8]. Output f32, same shape.
//
// R7: back to R4's measured-best structure (x register-resident -> minimal
// 805 MB fabric traffic; scalar dwords; 512thr = 8 slices x 64 px; CPT=24;
// launch_bounds(512,8)). Added: (1) nontemporal LOADS as well as stores --
// with x in registers there is ZERO cache reuse, so L2/L3 fills are pure
// pollution; pure-stream behavior is what the 7 TB/s fill kernel gets.
// (2) bijective chunked XCD swizzle (8192 blocks, %8==0): each XCD owns one
// image -> contiguous per-XCD address ranges (DRAM row locality).
// Evidence trail: time tracks fabric bytes (R2/R6 1.2GB ~ 206-211us;
// R4 805MB = 167us); occupancy >50% buys little (R6: 84% occ, slower).

#define N_IMG 8
#define C_CH 192
#define R_RK 8
#define HW 65536              // 256*256
#define PXB 64                // pixels per block
#define CSLICES 8
#define CPT (C_CH / CSLICES)  // 24 channels per thread
#define NTHR 512
#define BLOCKS_PER_IMG (HW / PXB)    // 1024
#define NBLK (N_IMG * BLOCKS_PER_IMG) // 8192

#define PEDESTAL_F 1.4551915228366852e-11f    // 2^-36
#define BOUND_A_F 3.814697265625e-06f         // 2^-18 = sqrt(pedestal)
#define BOUND_BETA_F 1.0000072759311364e-03f  // sqrt(1e-6 + 2^-36)

__global__ __launch_bounds__(NTHR, 8) void lrgdn_kernel(
    const float* __restrict__ x,
    const float* __restrict__ beta,
    const float* __restrict__ A,
    float* __restrict__ out)
{
    __shared__ float sA[C_CH][R_RK];          // reparametrized A (6 KB)
    __shared__ float sB[C_CH];                // reparametrized beta
    __shared__ float sT[CSLICES][R_RK][64];   // partial T (16 KB)

    const int tid = threadIdx.x;

    // Reparametrize params into LDS (tiny)
    for (int i = tid; i < C_CH * R_RK; i += NTHR) {
        float a = fmaxf(A[i], BOUND_A_F);
        sA[i >> 3][i & 7] = a * a - PEDESTAL_F;
    }
    if (tid < C_CH) {
        float b = fmaxf(beta[tid], BOUND_BETA_F);
        sB[tid] = b * b - PEDESTAL_F;
    }
    __syncthreads();

    // Chunked XCD swizzle: dispatch id b -> work id w so that each XCD
    // (b & 7) gets a contiguous 1024-block chunk = exactly one image.
    const int b = blockIdx.x;
    const int w = (b & 7) * (NBLK / 8) + (b >> 3);
    const int n    = w / BLOCKS_PER_IMG;
    const int p0   = (w % BLOCKS_PER_IMG) * PXB;
    const int lane = tid & 63;
    const int cs   = tid >> 6;          // channel slice 0..7 (uniform per wave)
    const int c0   = cs * CPT;

    const float* xn = x   + (size_t)n * (C_CH * HW) + p0 + (size_t)c0 * HW + lane;
    float*       on = out + (size_t)n * (C_CH * HW) + p0 + (size_t)c0 * HW + lane;

    // ---- load this thread's 24 channels into registers (nontemporal) ----
    float xr[CPT];
#pragma unroll
    for (int i = 0; i < CPT; ++i) {
        xr[i] = __builtin_nontemporal_load(xn + (size_t)i * HW);
    }

    // ---- accumulate partial T ----
    float T[R_RK];
#pragma unroll
    for (int r = 0; r < R_RK; ++r) T[r] = 0.f;

#pragma unroll
    for (int i = 0; i < CPT; ++i) {
        float s = xr[i] * xr[i];
#pragma unroll
        for (int r = 0; r < R_RK; ++r) {
            T[r] = fmaf(s, sA[c0 + i][r], T[r]);   // uniform LDS addr -> broadcast
        }
    }

    // ---- cross-slice reduce via LDS (one barrier) ----
#pragma unroll
    for (int r = 0; r < R_RK; ++r) {
        sT[cs][r][lane] = T[r];            // lanes consecutive: conflict-free
    }
    __syncthreads();

#pragma unroll
    for (int r = 0; r < R_RK; ++r) {
        float a01 = sT[0][r][lane] + sT[1][r][lane];
        float a23 = sT[2][r][lane] + sT[3][r][lane];
        float a45 = sT[4][r][lane] + sT[5][r][lane];
        float a67 = sT[6][r][lane] + sT[7][r][lane];
        T[r] = (a01 + a23) + (a45 + a67);
    }

    // ---- epilogue: denom + rsqrt + store (nontemporal), from registers ----
#pragma unroll
    for (int i = 0; i < CPT; ++i) {
        int c = c0 + i;
        float d = sB[c];
#pragma unroll
        for (int r = 0; r < R_RK; ++r) {
            d = fmaf(sA[c][r], T[r], d);
        }
        float o = xr[i] * __builtin_amdgcn_rsqf(d);
        __builtin_nontemporal_store(o, on + (size_t)i * HW);
    }
}

extern "C" void kernel_launch(void* const* d_in, const int* in_sizes, int n_in,
                              void* d_out, int out_size, void* d_ws, size_t ws_size,
                              hipStream_t stream) {
    const float* x    = (const float*)d_in[0];
    const float* beta = (const float*)d_in[1];
    const float* A    = (const float*)d_in[2];
    float* out = (float*)d_out;

    dim3 grid(NBLK);     // 8192 blocks
    dim3 block(NTHR);    // 512
    hipLaunchKernelGGL(lrgdn_kernel, grid, block, 0, stream, x, beta, A, out);
}